// Round 1
// baseline (895.414 us; speedup 1.0000x reference)
//
#include <hip/hip_runtime.h>
#include <hip/hip_bf16.h>
#include <stdint.h>

// Problem constants: L=S=2048, N=2, E=1024, H=16, hd=64
typedef short bf16x8 __attribute__((ext_vector_type(8)));
typedef float f32x4 __attribute__((ext_vector_type(4)));

__device__ __forceinline__ ushort f2bf(float f) {
  uint x = __float_as_uint(f);
  x += 0x7FFFu + ((x >> 16) & 1u);   // RNE (ignores NaN; inputs are finite)
  return (ushort)(x >> 16);
}

__device__ __forceinline__ uint cvt_pk_bf16(float lo, float hi) {
  uint r;
  asm("v_cvt_pk_bf16_f32 %0, %1, %2" : "=v"(r) : "v"(lo), "v"(hi));
  return r;
}

__device__ __forceinline__ void gl_lds16(const void* g, void* l) {
  __builtin_amdgcn_global_load_lds(
      (const __attribute__((address_space(1))) unsigned int*)g,
      (__attribute__((address_space(3))) unsigned int*)l, 16, 0, 0);
}

// ---------------------------------------------------------------------------
// Kernel 1: fp32 -> bf16 convert. Segments (query,key,value,Wqkv,Wo) are laid
// out contiguously in ws in the same order as the sources, so dst = ws + e.
// Total = 16,777,216 elems = 8192 blocks * 256 thr * 8 elems.
// ---------------------------------------------------------------------------
__global__ void __launch_bounds__(256) convert_bf16(
    const float* q, const float* k, const float* v,
    const float* ipw, const float* opw, ushort* dst) {
  size_t e = ((size_t)blockIdx.x * 256 + threadIdx.x) * 8;
  const float* src;
  if (e < 4194304u)        src = q   + e;
  else if (e < 8388608u)   src = k   + (e - 4194304u);
  else if (e < 12582912u)  src = v   + (e - 8388608u);
  else if (e < 15728640u)  src = ipw + (e - 12582912u);
  else                     src = opw + (e - 15728640u);
  float4 a = ((const float4*)src)[0];
  float4 b = ((const float4*)src)[1];
  uint4 o;
  o.x = cvt_pk_bf16(a.x, a.y);
  o.y = cvt_pk_bf16(a.z, a.w);
  o.z = cvt_pk_bf16(b.x, b.y);
  o.w = cvt_pk_bf16(b.z, b.w);
  *(uint4*)(dst + e) = o;
}

// ---------------------------------------------------------------------------
// Kernel 2/5: bf16 GEMM  C[4096 x 1024] = A[4096 x 1024] * W^T (+bias).
// 128x128 tile, BK=64, 4 waves (2x2), fragment-major LDS staging via
// global_load_lds (lane-linear ds_read_b128 -> conflict-free).
// mode 0: QKV projection; blockIdx.z = z in {q,k,v}; scatter to head layout.
// mode 1: out projection; fp32 store to (L,N,E).
// ---------------------------------------------------------------------------
__global__ void __launch_bounds__(256) gemm_bf16(
    const ushort* Abase, const ushort* W, const float* bias,
    ushort* oq, ushort* ok, ushort* ov, float* fout, int mode) {
  const int z = blockIdx.z;
  const ushort* A = Abase + (size_t)z * 4194304;
  const int rt = blockIdx.y, ct = blockIdx.x;
  const int tid = threadIdx.x, lane = tid & 63, wid = tid >> 6;
  const int g = lane >> 4, c = lane & 15;
  const int wr = wid >> 1, wc = wid & 1;

  __shared__ ushort Al[2][16 * 512];
  __shared__ ushort Bl[2][16 * 512];

  f32x4 acc[4][4];
#pragma unroll
  for (int i = 0; i < 4; i++)
#pragma unroll
    for (int j = 0; j < 4; j++) acc[i][j] = (f32x4){0.f, 0.f, 0.f, 0.f};

  auto stage = [&](int b, int k0) {
#pragma unroll
    for (int q2 = 0; q2 < 4; q2++) {
      int f = wid * 4 + q2;               // frag id: (fr, fm, fk)
      int fr = f >> 3, fm = (f >> 1) & 3, fk = f & 1;
      const ushort* asrc = A + (size_t)(rt * 128 + fr * 64 + fm * 16 + c) * 1024
                             + k0 + fk * 32 + g * 8;
      gl_lds16(asrc, (void*)&Al[b][f * 512]);
      const ushort* bsrc = W + (size_t)(z * 1024 + ct * 128 + fr * 64 + fm * 16 + c) * 1024
                             + k0 + fk * 32 + g * 8;
      gl_lds16(bsrc, (void*)&Bl[b][f * 512]);
    }
  };

  auto compute = [&](int b) {
#pragma unroll
    for (int kk = 0; kk < 2; kk++) {
      bf16x8 af[4], bfr[4];
#pragma unroll
      for (int mi = 0; mi < 4; mi++)
        af[mi] = *(const bf16x8*)&Al[b][(wr * 8 + mi * 2 + kk) * 512 + lane * 8];
#pragma unroll
      for (int ni = 0; ni < 4; ni++)
        bfr[ni] = *(const bf16x8*)&Bl[b][(wc * 8 + ni * 2 + kk) * 512 + lane * 8];
#pragma unroll
      for (int mi = 0; mi < 4; mi++)
#pragma unroll
        for (int ni = 0; ni < 4; ni++)
          acc[mi][ni] = __builtin_amdgcn_mfma_f32_16x16x32_bf16(af[mi], bfr[ni], acc[mi][ni], 0, 0, 0);
    }
  };

  stage(0, 0);
#pragma unroll 1
  for (int kt = 0; kt < 16; kt += 2) {
    __syncthreads();
    if (kt + 1 < 16) stage(1, (kt + 1) * 64);
    compute(0);
    __syncthreads();
    if (kt + 2 < 16) stage(0, (kt + 2) * 64);
    compute(1);
  }

  float bcol[4];
#pragma unroll
  for (int ni = 0; ni < 4; ni++)
    bcol[ni] = bias[z * 1024 + ct * 128 + wc * 64 + ni * 16 + c];

  if (mode == 0) {
    ushort* dst = (z == 0) ? oq : ((z == 1) ? ok : ov);
    float scl = (z == 0) ? 0.125f : 1.0f;   // q scaling = hd^-0.5
#pragma unroll
    for (int mi = 0; mi < 4; mi++)
#pragma unroll
      for (int r = 0; r < 4; r++) {
        int row = rt * 128 + wr * 64 + mi * 16 + g * 4 + r;  // row = t*2 + n
        int t = row >> 1, n = row & 1;
#pragma unroll
        for (int ni = 0; ni < 4; ni++) {
          int col = ct * 128 + wc * 64 + ni * 16 + c;        // col = h*64 + d
          int h = col >> 6, d = col & 63;
          float val = (acc[mi][ni][r] + bcol[ni]) * scl;
          dst[((size_t)(n * 16 + h) * 2048 + t) * 64 + d] = f2bf(val);
        }
      }
  } else {
#pragma unroll
    for (int mi = 0; mi < 4; mi++)
#pragma unroll
      for (int r = 0; r < 4; r++) {
        int row = rt * 128 + wr * 64 + mi * 16 + g * 4 + r;
#pragma unroll
        for (int ni = 0; ni < 4; ni++) {
          int col = ct * 128 + wc * 64 + ni * 16 + c;
          fout[(size_t)row * 1024 + col] = acc[mi][ni][r] + bcol[ni];
        }
      }
  }
}

// ---------------------------------------------------------------------------
// Kernel 3: per-head transpose vh (N,H,S,64) -> vhT (N,H,64,S).
// ---------------------------------------------------------------------------
__global__ void __launch_bounds__(256) transpose_v(const ushort* vh, ushort* vhT) {
  const int stile = blockIdx.x, nh = blockIdx.y;
  const int tid = threadIdx.x;
  __shared__ ushort T[64 * 72];
  {
    int s_loc = tid >> 2, dchunk = (tid & 3) * 16;
    const ushort* src = vh + ((size_t)nh * 2048 + stile * 64 + s_loc) * 64 + dchunk;
    union { uint4 u4[2]; ushort us[16]; } u;
    u.u4[0] = *(const uint4*)src;
    u.u4[1] = *(const uint4*)(src + 8);
#pragma unroll
    for (int j = 0; j < 16; j++) T[(dchunk + j) * 72 + s_loc] = u.us[j];
  }
  __syncthreads();
  {
    int d = tid >> 2, schunk = (tid & 3) * 16;
    uint4 o0 = *(const uint4*)&T[d * 72 + schunk];
    uint4 o1 = *(const uint4*)&T[d * 72 + schunk + 8];
    ushort* dst = vhT + ((size_t)nh * 64 + d) * 2048 + stile * 64 + schunk;
    *(uint4*)dst = o0;
    *(uint4*)(dst + 8) = o1;
  }
}

// ---------------------------------------------------------------------------
// Kernel 4: flash attention with additive bias (the 512 MiB stream).
// Swapped-operand QK^T: S^T = mfma(A=K, B=Q) so each lane owns ONE q-row
// (col = lane&15): softmax row-reduce = 2 shuffles; O-rescale per-lane-uniform.
// Block: 4 waves, QBLK=64 (16 rows/wave), KVBLK=64, 32 s-tiles, 1 barrier/iter.
// K and V^T staged fragment-major via global_load_lds (conflict-free b128).
// Bias float4-loaded directly into the MFMA accumulator init.
// ---------------------------------------------------------------------------
__global__ void __launch_bounds__(256) flash_attn(
    const ushort* qh, const ushort* kh, const ushort* vhT,
    const float* bias, ushort* attnO) {
  const int qt = blockIdx.x, nh = blockIdx.y;
  const int tid = threadIdx.x, lane = tid & 63, w = tid >> 6;
  const int g = lane >> 4, c = lane & 15;
  const int l = qt * 64 + w * 16 + c;      // this lane's q-row
  const int n = nh >> 4, h = nh & 15;

  const ushort* q_nh = qh + (size_t)nh * 2048 * 64;
  const ushort* k_nh = kh + (size_t)nh * 2048 * 64;
  const ushort* v_nh = vhT + (size_t)nh * 64 * 2048;
  const float4* b4 = (const float4*)(bias + (size_t)nh * 2048 * 2048);

  __shared__ ushort Kl[2][8 * 512];
  __shared__ ushort Vl[2][8 * 512];

  bf16x8 qf[2];
#pragma unroll
  for (int kk = 0; kk < 2; kk++)
    qf[kk] = *(const bf16x8*)(q_nh + (size_t)l * 64 + kk * 32 + g * 8);

  f32x4 Oa[4];
#pragma unroll
  for (int ni = 0; ni < 4; ni++) Oa[ni] = (f32x4){0.f, 0.f, 0.f, 0.f};
  float m_run = -1e30f, l_run = 0.f;

  auto stage = [&](int b, int t) {
    int s0 = t * 64;
#pragma unroll
    for (int q2 = 0; q2 < 2; q2++) {
      int f = w + q2 * 4;                          // (mi = f&3, kk = f>>2)
      const ushort* ks = k_nh + (size_t)(s0 + (f & 3) * 16 + c) * 64 + (f >> 2) * 32 + g * 8;
      gl_lds16(ks, (void*)&Kl[b][f * 512]);
      const ushort* vs = v_nh + (size_t)((f & 3) * 16 + c) * 2048 + s0 + (f >> 2) * 32 + g * 8;
      gl_lds16(vs, (void*)&Vl[b][f * 512]);
    }
  };

  auto loadbias = [&](float4* bb, int t) {
#pragma unroll
    for (int mi = 0; mi < 4; mi++)
      bb[mi] = b4[(size_t)l * 512 + t * 16 + mi * 4 + g];
  };

  auto compute = [&](int b, const float4* bb) {
    // scores S^T[s][l]: C-init = bias[l][s]  (s = mi*16 + g*4 + r)
    f32x4 sc[4];
#pragma unroll
    for (int mi = 0; mi < 4; mi++)
      sc[mi] = (f32x4){bb[mi].x, bb[mi].y, bb[mi].z, bb[mi].w};
#pragma unroll
    for (int kk = 0; kk < 2; kk++)
#pragma unroll
      for (int mi = 0; mi < 4; mi++) {
        bf16x8 kf = *(const bf16x8*)&Kl[b][(kk * 4 + mi) * 512 + lane * 8];
        sc[mi] = __builtin_amdgcn_mfma_f32_16x16x32_bf16(kf, qf[kk], sc[mi], 0, 0, 0);
      }
    // online softmax over this lane's column (its q-row)
    float mx = -1e30f;
#pragma unroll
    for (int mi = 0; mi < 4; mi++)
#pragma unroll
      for (int r = 0; r < 4; r++) mx = fmaxf(mx, sc[mi][r]);
    mx = fmaxf(mx, __shfl_xor(mx, 16, 64));
    mx = fmaxf(mx, __shfl_xor(mx, 32, 64));
    float m_new = fmaxf(m_run, mx);
    const float L2E = 1.4426950408889634f;
    float corr = __builtin_amdgcn_exp2f((m_run - m_new) * L2E);
    float psum = 0.f;
#pragma unroll
    for (int mi = 0; mi < 4; mi++)
#pragma unroll
      for (int r = 0; r < 4; r++) {
        float p = __builtin_amdgcn_exp2f((sc[mi][r] - m_new) * L2E);
        sc[mi][r] = p;
        psum += p;
      }
    psum += __shfl_xor(psum, 16, 64);
    psum += __shfl_xor(psum, 32, 64);
    l_run = l_run * corr + psum;
    m_run = m_new;
#pragma unroll
    for (int ni = 0; ni < 4; ni++) Oa[ni] *= corr;

    // pack P^T to bf16 and redistribute C-layout -> B-fragment layout
    uint pk[4][2];
#pragma unroll
    for (int mi = 0; mi < 4; mi++) {
      pk[mi][0] = cvt_pk_bf16(sc[mi][0], sc[mi][1]);
      pk[mi][1] = cvt_pk_bf16(sc[mi][2], sc[mi][3]);
    }
    const int sgb = ((g & 1) * 2) * 16 + c;
    const bool hi = (g >= 2);
#pragma unroll
    for (int kks = 0; kks < 2; kks++) {
      uint dw[4];
#pragma unroll
      for (int j = 0; j < 4; j++) {
        int src = sgb + (j >> 1) * 16;
        uint a0 = (uint)__shfl((int)pk[2 * kks + 0][j & 1], src, 64);
        uint a1 = (uint)__shfl((int)pk[2 * kks + 1][j & 1], src, 64);
        dw[j] = hi ? a1 : a0;
      }
      union { uint u[4]; bf16x8 v; } pb;
      pb.u[0] = dw[0]; pb.u[1] = dw[1]; pb.u[2] = dw[2]; pb.u[3] = dw[3];
#pragma unroll
      for (int ni = 0; ni < 4; ni++) {
        bf16x8 vf = *(const bf16x8*)&Vl[b][(kks * 4 + ni) * 512 + lane * 8];
        Oa[ni] = __builtin_amdgcn_mfma_f32_16x16x32_bf16(vf, pb.v, Oa[ni], 0, 0, 0);
      }
    }
  };

  float4 biasA[4], biasB[4];
  stage(0, 0);
  loadbias(biasA, 0);
#pragma unroll 1
  for (int t = 0; t < 32; t += 2) {
    __syncthreads();
    if (t + 1 < 32) { stage(1, t + 1); loadbias(biasB, t + 1); }
    compute(0, biasA);
    __syncthreads();
    if (t + 2 < 32) { stage(0, t + 2); loadbias(biasA, t + 2); }
    compute(1, biasB);
  }

  float inv = 1.0f / l_run;
  size_t obase = ((size_t)(l * 2 + n)) * 1024 + h * 64;
#pragma unroll
  for (int ni = 0; ni < 4; ni++) {
    ushort4 o;
    o.x = f2bf(Oa[ni][0] * inv);
    o.y = f2bf(Oa[ni][1] * inv);
    o.z = f2bf(Oa[ni][2] * inv);
    o.w = f2bf(Oa[ni][3] * inv);
    *(ushort4*)(attnO + obase + ni * 16 + g * 4) = o;
  }
}

// ---------------------------------------------------------------------------
// Workspace layout (bf16 elems):
//   0        Xq (4M)   -> reused later as vhT
//   4194304  Xk (4M)   -> reused later as attnO
//   8388608  Xv (4M)
//   12582912 Wqkv (3M)
//   15728640 Wo (1M)
//   16777216 qh (4M)
//   20971520 kh (4M)
//   25165824 vh (4M)     total = 56 MiB
// ---------------------------------------------------------------------------
extern "C" void kernel_launch(void* const* d_in, const int* in_sizes, int n_in,
                              void* d_out, int out_size, void* d_ws, size_t ws_size,
                              hipStream_t stream) {
  (void)in_sizes; (void)n_in; (void)out_size; (void)ws_size;
  const float* query = (const float*)d_in[0];
  const float* key   = (const float*)d_in[1];
  const float* value = (const float*)d_in[2];
  const float* abias = (const float*)d_in[3];
  const float* ipw   = (const float*)d_in[4];
  const float* ipb   = (const float*)d_in[5];
  const float* opw   = (const float*)d_in[6];
  const float* opb   = (const float*)d_in[7];
  float* out = (float*)d_out;

  ushort* ws   = (ushort*)d_ws;
  ushort* Xq   = ws;
  ushort* Wqkv = ws + 12582912;
  ushort* Wo   = ws + 15728640;
  ushort* qh   = ws + 16777216;
  ushort* kh   = ws + 20971520;
  ushort* vh   = ws + 25165824;
  ushort* vhT  = ws;             // reuse Xq region
  ushort* attnO = ws + 4194304;  // reuse Xk region

  convert_bf16<<<8192, 256, 0, stream>>>(query, key, value, ipw, opw, ws);
  gemm_bf16<<<dim3(8, 32, 3), 256, 0, stream>>>(Xq, Wqkv, ipb, qh, kh, vh, nullptr, 0);
  transpose_v<<<dim3(32, 32), 256, 0, stream>>>(vh, vhT);
  flash_attn<<<dim3(32, 32), 256, 0, stream>>>(qh, kh, vhT, abias, attnO);
  gemm_bf16<<<dim3(8, 32, 1), 256, 0, stream>>>(attnO, Wo, opb, nullptr, nullptr, nullptr, out, 1);
}

// Round 2
// 889.173 us; speedup vs baseline: 1.0070x; 1.0070x over previous
//
#include <hip/hip_runtime.h>
#include <hip/hip_bf16.h>
#include <stdint.h>

// Problem constants: L=S=2048, N=2, E=1024, H=16, hd=64
typedef short bf16x8 __attribute__((ext_vector_type(8)));
typedef float f32x4 __attribute__((ext_vector_type(4)));

__device__ __forceinline__ ushort f2bf(float f) {
  uint x = __float_as_uint(f);
  x += 0x7FFFu + ((x >> 16) & 1u);   // RNE (ignores NaN; inputs are finite)
  return (ushort)(x >> 16);
}

__device__ __forceinline__ uint cvt_pk_bf16(float lo, float hi) {
  uint r;
  asm("v_cvt_pk_bf16_f32 %0, %1, %2" : "=v"(r) : "v"(lo), "v"(hi));
  return r;
}

__device__ __forceinline__ void gl_lds16(const void* g, void* l) {
  __builtin_amdgcn_global_load_lds(
      (const __attribute__((address_space(1))) unsigned int*)g,
      (__attribute__((address_space(3))) unsigned int*)l, 16, 0, 0);
}

// ---------------------------------------------------------------------------
// Kernel 1: fp32 -> bf16 convert. Segments (query,key,value,Wqkv,Wo) are laid
// out contiguously in ws in the same order as the sources, so dst = ws + e.
// Total = 16,777,216 elems = 8192 blocks * 256 thr * 8 elems.
// ---------------------------------------------------------------------------
__global__ void __launch_bounds__(256) convert_bf16(
    const float* q, const float* k, const float* v,
    const float* ipw, const float* opw, ushort* dst) {
  size_t e = ((size_t)blockIdx.x * 256 + threadIdx.x) * 8;
  const float* src;
  if (e < 4194304u)        src = q   + e;
  else if (e < 8388608u)   src = k   + (e - 4194304u);
  else if (e < 12582912u)  src = v   + (e - 8388608u);
  else if (e < 15728640u)  src = ipw + (e - 12582912u);
  else                     src = opw + (e - 15728640u);
  float4 a = ((const float4*)src)[0];
  float4 b = ((const float4*)src)[1];
  uint4 o;
  o.x = cvt_pk_bf16(a.x, a.y);
  o.y = cvt_pk_bf16(a.z, a.w);
  o.z = cvt_pk_bf16(b.x, b.y);
  o.w = cvt_pk_bf16(b.z, b.w);
  *(uint4*)(dst + e) = o;
}

// ---------------------------------------------------------------------------
// Kernel 2/5: bf16 GEMM  C[4096 x 1024] = A[4096 x 1024] * W^T (+bias).
// 128x128 tile, BK=64, 4 waves (2x2), fragment-major LDS staging via
// global_load_lds (lane-linear ds_read_b128 -> conflict-free).
// mode 0: QKV projection; blockIdx.z = z in {q,k,v}; scatter to head layout.
// mode 1: out projection; fp32 store to (L,N,E).
// ---------------------------------------------------------------------------
__global__ void __launch_bounds__(256) gemm_bf16(
    const ushort* Abase, const ushort* W, const float* bias,
    ushort* oq, ushort* ok, ushort* ov, float* fout, int mode) {
  const int z = blockIdx.z;
  const ushort* A = Abase + (size_t)z * 4194304;
  const int rt = blockIdx.y, ct = blockIdx.x;
  const int tid = threadIdx.x, lane = tid & 63, wid = tid >> 6;
  const int g = lane >> 4, c = lane & 15;
  const int wr = wid >> 1, wc = wid & 1;

  __shared__ ushort Al[2][16 * 512];
  __shared__ ushort Bl[2][16 * 512];

  f32x4 acc[4][4];
#pragma unroll
  for (int i = 0; i < 4; i++)
#pragma unroll
    for (int j = 0; j < 4; j++) acc[i][j] = (f32x4){0.f, 0.f, 0.f, 0.f};

  auto stage = [&](int b, int k0) {
#pragma unroll
    for (int q2 = 0; q2 < 4; q2++) {
      int f = wid * 4 + q2;               // frag id: (fr, fm, fk)
      int fr = f >> 3, fm = (f >> 1) & 3, fk = f & 1;
      const ushort* asrc = A + (size_t)(rt * 128 + fr * 64 + fm * 16 + c) * 1024
                             + k0 + fk * 32 + g * 8;
      gl_lds16(asrc, (void*)&Al[b][f * 512]);
      const ushort* bsrc = W + (size_t)(z * 1024 + ct * 128 + fr * 64 + fm * 16 + c) * 1024
                             + k0 + fk * 32 + g * 8;
      gl_lds16(bsrc, (void*)&Bl[b][f * 512]);
    }
  };

  auto compute = [&](int b) {
#pragma unroll
    for (int kk = 0; kk < 2; kk++) {
      bf16x8 af[4], bfr[4];
#pragma unroll
      for (int mi = 0; mi < 4; mi++)
        af[mi] = *(const bf16x8*)&Al[b][(wr * 8 + mi * 2 + kk) * 512 + lane * 8];
#pragma unroll
      for (int ni = 0; ni < 4; ni++)
        bfr[ni] = *(const bf16x8*)&Bl[b][(wc * 8 + ni * 2 + kk) * 512 + lane * 8];
#pragma unroll
      for (int mi = 0; mi < 4; mi++)
#pragma unroll
        for (int ni = 0; ni < 4; ni++)
          acc[mi][ni] = __builtin_amdgcn_mfma_f32_16x16x32_bf16(af[mi], bfr[ni], acc[mi][ni], 0, 0, 0);
    }
  };

  stage(0, 0);
#pragma unroll 1
  for (int kt = 0; kt < 16; kt += 2) {
    __syncthreads();
    if (kt + 1 < 16) stage(1, (kt + 1) * 64);
    compute(0);
    __syncthreads();
    if (kt + 2 < 16) stage(0, (kt + 2) * 64);
    compute(1);
  }

  float bcol[4];
#pragma unroll
  for (int ni = 0; ni < 4; ni++)
    bcol[ni] = bias[z * 1024 + ct * 128 + wc * 64 + ni * 16 + c];

  if (mode == 0) {
    ushort* dst = (z == 0) ? oq : ((z == 1) ? ok : ov);
    float scl = (z == 0) ? 0.125f : 1.0f;   // q scaling = hd^-0.5
#pragma unroll
    for (int mi = 0; mi < 4; mi++)
#pragma unroll
      for (int r = 0; r < 4; r++) {
        int row = rt * 128 + wr * 64 + mi * 16 + g * 4 + r;  // row = t*2 + n
        int t = row >> 1, n = row & 1;
#pragma unroll
        for (int ni = 0; ni < 4; ni++) {
          int col = ct * 128 + wc * 64 + ni * 16 + c;        // col = h*64 + d
          int h = col >> 6, d = col & 63;
          float val = (acc[mi][ni][r] + bcol[ni]) * scl;
          dst[((size_t)(n * 16 + h) * 2048 + t) * 64 + d] = f2bf(val);
        }
      }
  } else {
#pragma unroll
    for (int mi = 0; mi < 4; mi++)
#pragma unroll
      for (int r = 0; r < 4; r++) {
        int row = rt * 128 + wr * 64 + mi * 16 + g * 4 + r;
#pragma unroll
        for (int ni = 0; ni < 4; ni++) {
          int col = ct * 128 + wc * 64 + ni * 16 + c;
          fout[(size_t)row * 1024 + col] = acc[mi][ni][r] + bcol[ni];
        }
      }
  }
}

// ---------------------------------------------------------------------------
// Kernel 3: per-head transpose vh (N,H,S,64) -> vhT (N,H,64,S).
// ---------------------------------------------------------------------------
__global__ void __launch_bounds__(256) transpose_v(const ushort* vh, ushort* vhT) {
  const int stile = blockIdx.x, nh = blockIdx.y;
  const int tid = threadIdx.x;
  __shared__ ushort T[64 * 72];
  {
    int s_loc = tid >> 2, dchunk = (tid & 3) * 16;
    const ushort* src = vh + ((size_t)nh * 2048 + stile * 64 + s_loc) * 64 + dchunk;
    union { uint4 u4[2]; ushort us[16]; } u;
    u.u4[0] = *(const uint4*)src;
    u.u4[1] = *(const uint4*)(src + 8);
#pragma unroll
    for (int j = 0; j < 16; j++) T[(dchunk + j) * 72 + s_loc] = u.us[j];
  }
  __syncthreads();
  {
    int d = tid >> 2, schunk = (tid & 3) * 16;
    uint4 o0 = *(const uint4*)&T[d * 72 + schunk];
    uint4 o1 = *(const uint4*)&T[d * 72 + schunk + 8];
    ushort* dst = vhT + ((size_t)nh * 64 + d) * 2048 + stile * 64 + schunk;
    *(uint4*)dst = o0;
    *(uint4*)(dst + 8) = o1;
  }
}

// ---------------------------------------------------------------------------
// Kernel 4: flash attention with additive bias (the 512 MiB stream).
// Swapped-operand QK^T: S^T = mfma(A=K, B=Q) so each lane owns ONE q-row
// (col = lane&15): softmax row-reduce = 2 shuffles; O-rescale per-lane-uniform.
// Block: 4 waves, QBLK=64 (16 rows/wave), KVBLK=64, 32 s-tiles, 1 barrier/iter.
// K, V^T AND the fp32 bias tile staged via global_load_lds, double-buffered.
// Bias tile [64 l][16 col4] staged with XOR-swizzled SOURCE addresses
// (col4 ^= row&15) so the lane-linear LDS dest yields 2-way-free ds_read_b128.
// ---------------------------------------------------------------------------
__global__ void __launch_bounds__(256) flash_attn(
    const ushort* qh, const ushort* kh, const ushort* vhT,
    const float* bias, ushort* attnO) {
  const int qt = blockIdx.x, nh = blockIdx.y;
  const int tid = threadIdx.x, lane = tid & 63, w = tid >> 6;
  const int g = lane >> 4, c = lane & 15;
  const int l = qt * 64 + w * 16 + c;      // this lane's q-row (global)
  const int lloc = w * 16 + c;             // this lane's q-row (tile-local)
  const int n = nh >> 4, h = nh & 15;

  const ushort* q_nh = qh + (size_t)nh * 2048 * 64;
  const ushort* k_nh = kh + (size_t)nh * 2048 * 64;
  const ushort* v_nh = vhT + (size_t)nh * 64 * 2048;
  const float* bias_nh = bias + (size_t)nh * 2048 * 2048;

  __shared__ ushort Kl[2][8 * 512];
  __shared__ ushort Vl[2][8 * 512];
  __shared__ float Bi[2][64 * 64];

  bf16x8 qf[2];
#pragma unroll
  for (int kk = 0; kk < 2; kk++)
    qf[kk] = *(const bf16x8*)(q_nh + (size_t)l * 64 + kk * 32 + g * 8);

  f32x4 Oa[4];
#pragma unroll
  for (int ni = 0; ni < 4; ni++) Oa[ni] = (f32x4){0.f, 0.f, 0.f, 0.f};
  float m_run = -1e30f, l_run = 0.f;

  auto stage = [&](int b, int t) {
    int s0 = t * 64;
#pragma unroll
    for (int q2 = 0; q2 < 2; q2++) {
      int f = w + q2 * 4;                          // (mi = f&3, kk = f>>2)
      const ushort* ks = k_nh + (size_t)(s0 + (f & 3) * 16 + c) * 64 + (f >> 2) * 32 + g * 8;
      gl_lds16(ks, (void*)&Kl[b][f * 512]);
      const ushort* vs = v_nh + (size_t)((f & 3) * 16 + c) * 2048 + s0 + (f >> 2) * 32 + g * 8;
      gl_lds16(vs, (void*)&Vl[b][f * 512]);
    }
    // bias tile [64 rows][64 cols] fp32, 16 KB: 4 passes x 4 waves x 64 lanes
    // x 16B. Lane-linear dest; swizzle applied on SOURCE col4.
#pragma unroll
    for (int p = 0; p < 4; p++) {
      int idxb = p * 256 + w * 64;                 // wave-uniform
      int idx = idxb + lane;
      int row = idx >> 4;
      int c4 = (idx & 15) ^ (row & 15);
      const float* bs = bias_nh + (size_t)(qt * 64 + row) * 2048 + s0 + c4 * 4;
      gl_lds16(bs, (void*)&Bi[b][idxb * 4]);
    }
  };

  auto compute = [&](int b) {
    // scores S^T[s][l]: C-init = bias[l][s]  (s = mi*16 + g*4 + r)
    f32x4 sc[4];
#pragma unroll
    for (int mi = 0; mi < 4; mi++) {
      int s4 = (mi * 4 + g) ^ (lloc & 15);
      float4 bb = *(const float4*)&Bi[b][(lloc * 16 + s4) * 4];
      sc[mi] = (f32x4){bb.x, bb.y, bb.z, bb.w};
    }
#pragma unroll
    for (int kk = 0; kk < 2; kk++)
#pragma unroll
      for (int mi = 0; mi < 4; mi++) {
        bf16x8 kf = *(const bf16x8*)&Kl[b][(kk * 4 + mi) * 512 + lane * 8];
        sc[mi] = __builtin_amdgcn_mfma_f32_16x16x32_bf16(kf, qf[kk], sc[mi], 0, 0, 0);
      }
    // online softmax over this lane's column (its q-row)
    float mx = -1e30f;
#pragma unroll
    for (int mi = 0; mi < 4; mi++)
#pragma unroll
      for (int r = 0; r < 4; r++) mx = fmaxf(mx, sc[mi][r]);
    mx = fmaxf(mx, __shfl_xor(mx, 16, 64));
    mx = fmaxf(mx, __shfl_xor(mx, 32, 64));
    float m_new = fmaxf(m_run, mx);
    const float L2E = 1.4426950408889634f;
    float corr = __builtin_amdgcn_exp2f((m_run - m_new) * L2E);
    float psum = 0.f;
#pragma unroll
    for (int mi = 0; mi < 4; mi++)
#pragma unroll
      for (int r = 0; r < 4; r++) {
        float p = __builtin_amdgcn_exp2f((sc[mi][r] - m_new) * L2E);
        sc[mi][r] = p;
        psum += p;
      }
    psum += __shfl_xor(psum, 16, 64);
    psum += __shfl_xor(psum, 32, 64);
    l_run = l_run * corr + psum;
    m_run = m_new;
#pragma unroll
    for (int ni = 0; ni < 4; ni++) Oa[ni] *= corr;

    // pack P^T to bf16 and redistribute C-layout -> B-fragment layout
    uint pk[4][2];
#pragma unroll
    for (int mi = 0; mi < 4; mi++) {
      pk[mi][0] = cvt_pk_bf16(sc[mi][0], sc[mi][1]);
      pk[mi][1] = cvt_pk_bf16(sc[mi][2], sc[mi][3]);
    }
    const int sgb = ((g & 1) * 2) * 16 + c;
    const bool hi = (g >= 2);
#pragma unroll
    for (int kks = 0; kks < 2; kks++) {
      uint dw[4];
#pragma unroll
      for (int j = 0; j < 4; j++) {
        int src = sgb + (j >> 1) * 16;
        uint a0 = (uint)__shfl((int)pk[2 * kks + 0][j & 1], src, 64);
        uint a1 = (uint)__shfl((int)pk[2 * kks + 1][j & 1], src, 64);
        dw[j] = hi ? a1 : a0;
      }
      union { uint u[4]; bf16x8 v; } pb;
      pb.u[0] = dw[0]; pb.u[1] = dw[1]; pb.u[2] = dw[2]; pb.u[3] = dw[3];
#pragma unroll
      for (int ni = 0; ni < 4; ni++) {
        bf16x8 vf = *(const bf16x8*)&Vl[b][(kks * 4 + ni) * 512 + lane * 8];
        Oa[ni] = __builtin_amdgcn_mfma_f32_16x16x32_bf16(vf, pb.v, Oa[ni], 0, 0, 0);
      }
    }
  };

  stage(0, 0);
#pragma unroll 1
  for (int t = 0; t < 32; t += 2) {
    __syncthreads();
    if (t + 1 < 32) stage(1, t + 1);
    compute(0);
    __syncthreads();
    if (t + 2 < 32) stage(0, t + 2);
    compute(1);
  }

  float inv = 1.0f / l_run;
  size_t obase = ((size_t)(l * 2 + n)) * 1024 + h * 64;
#pragma unroll
  for (int ni = 0; ni < 4; ni++) {
    ushort4 o;
    o.x = f2bf(Oa[ni][0] * inv);
    o.y = f2bf(Oa[ni][1] * inv);
    o.z = f2bf(Oa[ni][2] * inv);
    o.w = f2bf(Oa[ni][3] * inv);
    *(ushort4*)(attnO + obase + ni * 16 + g * 4) = o;
  }
}

// ---------------------------------------------------------------------------
// Workspace layout (bf16 elems):
//   0        Xq (4M)   -> reused later as vhT
//   4194304  Xk (4M)   -> reused later as attnO
//   8388608  Xv (4M)
//   12582912 Wqkv (3M)
//   15728640 Wo (1M)
//   16777216 qh (4M)
//   20971520 kh (4M)
//   25165824 vh (4M)     total = 56 MiB
// ---------------------------------------------------------------------------
extern "C" void kernel_launch(void* const* d_in, const int* in_sizes, int n_in,
                              void* d_out, int out_size, void* d_ws, size_t ws_size,
                              hipStream_t stream) {
  (void)in_sizes; (void)n_in; (void)out_size; (void)ws_size;
  const float* query = (const float*)d_in[0];
  const float* key   = (const float*)d_in[1];
  const float* value = (const float*)d_in[2];
  const float* abias = (const float*)d_in[3];
  const float* ipw   = (const float*)d_in[4];
  const float* ipb   = (const float*)d_in[5];
  const float* opw   = (const float*)d_in[6];
  const float* opb   = (const float*)d_in[7];
  float* out = (float*)d_out;

  ushort* ws   = (ushort*)d_ws;
  ushort* Xq   = ws;
  ushort* Wqkv = ws + 12582912;
  ushort* Wo   = ws + 15728640;
  ushort* qh   = ws + 16777216;
  ushort* kh   = ws + 20971520;
  ushort* vh   = ws + 25165824;
  ushort* vhT  = ws;             // reuse Xq region
  ushort* attnO = ws + 4194304;  // reuse Xk region

  convert_bf16<<<8192, 256, 0, stream>>>(query, key, value, ipw, opw, ws);
  gemm_bf16<<<dim3(8, 32, 3), 256, 0, stream>>>(Xq, Wqkv, ipb, qh, kh, vh, nullptr, 0);
  transpose_v<<<dim3(32, 32), 256, 0, stream>>>(vh, vhT);
  flash_attn<<<dim3(32, 32), 256, 0, stream>>>(qh, kh, vhT, abias, attnO);
  gemm_bf16<<<dim3(8, 32, 1), 256, 0, stream>>>(attnO, Wo, opb, nullptr, nullptr, nullptr, out, 1);
}